// Round 1
// baseline (1640.928 us; speedup 1.0000x reference)
//
#include <hip/hip_runtime.h>
#include <math.h>

#define Nn   100000
#define Ee   1600000
#define FIN  128
#define DIM  64
#define NCL  40
#define NHE  50000

// ---------------- GEMM: x[N][128] @ W[128][64] -> out[N][64] ----------------
__global__ __launch_bounds__(512) void gemm_x_w1(const float* __restrict__ x,
                                                 const float* __restrict__ W,
                                                 float* __restrict__ out) {
    __shared__ float Ws[FIN * DIM];   // 32 KB
    __shared__ float xs[8][FIN];      // 4 KB
    int tid = threadIdx.x;
    for (int i = tid; i < FIN * DIM; i += 512) Ws[i] = W[i];
    int row0 = blockIdx.x * 8;
    for (int i = tid; i < 8 * FIN; i += 512) {
        int r = i >> 7, k = i & (FIN - 1);
        int row = row0 + r;
        xs[r][k] = (row < Nn) ? x[(size_t)row * FIN + k] : 0.f;
    }
    __syncthreads();
    int f = tid & 63, r = tid >> 6;
    int row = row0 + r;
    if (row < Nn) {
        float acc = 0.f;
#pragma unroll
        for (int k = 0; k < FIN; ++k) acc = fmaf(xs[r][k], Ws[k * DIM + f], acc);
        out[(size_t)row * DIM + f] = acc;
    }
}

// ---------------- GEMM: xh[N][64] @ W[64][40] -> out[N][40] ----------------
__global__ __launch_bounds__(320) void gemm_h_w2(const float* __restrict__ xh,
                                                 const float* __restrict__ W,
                                                 float* __restrict__ out) {
    __shared__ float Ws[DIM * NCL];   // 10 KB
    __shared__ float xs[8][DIM];      // 2 KB
    int tid = threadIdx.x;  // 0..319
    for (int i = tid; i < DIM * NCL; i += 320) Ws[i] = W[i];
    int row0 = blockIdx.x * 8;
    for (int i = tid; i < 8 * DIM; i += 320) {
        int r = i >> 6, k = i & 63;
        int row = row0 + r;
        xs[r][k] = (row < Nn) ? xh[(size_t)row * DIM + k] : 0.f;
    }
    __syncthreads();
    int f = tid % NCL, r = tid / NCL;
    int row = row0 + r;
    if (row < Nn) {
        float acc = 0.f;
#pragma unroll
        for (int k = 0; k < DIM; ++k) acc = fmaf(xs[r][k], Ws[k * NCL + f], acc);
        out[(size_t)row * NCL + f] = acc;
    }
}

// ---------------- degree counting ----------------
__global__ void count_deg(const int* __restrict__ hn, const int* __restrict__ he,
                          float* __restrict__ D, float* __restrict__ B) {
    int i = blockIdx.x * blockDim.x + threadIdx.x;
    if (i < Ee) {
        atomicAdd(&D[hn[i]], 1.0f);
        atomicAdd(&B[he[i]], 1.0f);
    }
}

// ---------------- node -> hyperedge scatter: dst[sidx[e]] += src[gidx[e]] ----------------
template <int F>
__global__ void scat_fwd(const float* __restrict__ src, const int* __restrict__ gidx,
                         const int* __restrict__ sidx, float* __restrict__ dst) {
    int e = blockIdx.x * 4 + (threadIdx.x >> 6);
    int f = threadIdx.x & 63;
    if (e >= Ee || f >= F) return;
    int g = gidx[e], s = sidx[e];
    atomicAdd(&dst[(size_t)s * F + f], src[(size_t)g * F + f]);
}

// ---------------- hyperedge -> node scatter with Binv fold ----------------
template <int F>
__global__ void scat_bwd(const float* __restrict__ me, const int* __restrict__ he,
                         const int* __restrict__ hn, const float* __restrict__ B,
                         float* __restrict__ dst) {
    int e = blockIdx.x * 4 + (threadIdx.x >> 6);
    int f = threadIdx.x & 63;
    if (e >= Ee || f >= F) return;
    int h = he[e], n = hn[e];
    float binv = 1.0f / B[h];   // h appears => B[h] >= 1
    atomicAdd(&dst[(size_t)n * F + f], me[(size_t)h * F + f] * binv);
}

// ---------------- finish: out = (acc * Dinv + bias) [relu] ----------------
template <int F, bool RELU>
__global__ void finish_k(const float* __restrict__ acc, const float* __restrict__ D,
                         const float* __restrict__ bias, float* __restrict__ out) {
    long long idx = (long long)blockIdx.x * blockDim.x + threadIdx.x;
    if (idx >= (long long)Nn * F) return;
    int n = (int)(idx / F);
    int f = (int)(idx - (long long)n * F);
    float d = D[n];
    float dinv = d > 0.f ? 1.0f / d : 0.f;
    float v = acc[idx] * dinv + bias[f];
    if (RELU) v = fmaxf(v, 0.f);
    out[idx] = v;
}

// ---------------- head: ((xh2 @ Wv + bv) @ Wo + bo) -> log_softmax ----------------
__global__ __launch_bounds__(64) void head_k(const float* __restrict__ xh2,
                                             const float* __restrict__ Wv, const float* __restrict__ bv,
                                             const float* __restrict__ Wo, const float* __restrict__ bo,
                                             float* __restrict__ out) {
    __shared__ float row[NCL];
    __shared__ float vbuf[NCL];
    int n = blockIdx.x;
    int t = threadIdx.x;
    if (t < NCL) row[t] = xh2[(size_t)n * NCL + t];
    __syncthreads();
    if (t < NCL) {
        float vv = bv[t];
#pragma unroll
        for (int k = 0; k < NCL; ++k) vv = fmaf(row[k], Wv[k * NCL + t], vv);
        vbuf[t] = vv;
    }
    __syncthreads();
    float o = -INFINITY;
    if (t < NCL) {
        o = bo[t];
#pragma unroll
        for (int k = 0; k < NCL; ++k) o = fmaf(vbuf[k], Wo[k * NCL + t], o);
    }
    // log_softmax over the 40 active lanes (butterfly over full wave)
    float m = o;
#pragma unroll
    for (int off = 32; off >= 1; off >>= 1) m = fmaxf(m, __shfl_xor(m, off));
    float ex = (t < NCL) ? expf(o - m) : 0.f;
    float s = ex;
#pragma unroll
    for (int off = 32; off >= 1; off >>= 1) s += __shfl_xor(s, off);
    if (t < NCL) out[(size_t)n * NCL + t] = o - m - logf(s);
}

extern "C" void kernel_launch(void* const* d_in, const int* in_sizes, int n_in,
                              void* d_out, int out_size, void* d_ws, size_t ws_size,
                              hipStream_t stream) {
    (void)in_sizes; (void)n_in; (void)out_size; (void)ws_size;

    const float* x   = (const float*)d_in[0];
    const int*   hn  = (const int*)d_in[2];
    const int*   he  = (const int*)d_in[3];
    const float* Wh1 = (const float*)d_in[6];
    const float* bh1 = (const float*)d_in[7];
    const float* Wh2 = (const float*)d_in[18];
    const float* bh2 = (const float*)d_in[19];
    const float* Wv2 = (const float*)d_in[24];
    const float* bv2 = (const float*)d_in[25];
    const float* Wo2 = (const float*)d_in[26];
    const float* bo2 = (const float*)d_in[27];
    float* out = (float*)d_out;

    // workspace layout (floats): total 20,150,000 floats = 80.6 MB
    float* P0 = (float*)d_ws;                    // N*64 : xw1, then x_hyper, then x_hyper2
    float* P1 = P0 + (size_t)Nn * DIM;           // N*64 : acc1, then acc2 (N*40)
    float* P2 = P1 + (size_t)Nn * DIM;           // NHE*64 : m_e1, then m_e2 (NHE*40)
    float* P3 = P2 + (size_t)NHE * DIM;          // N*40 : xw2
    float* Dd = P3 + (size_t)Nn * NCL;           // N : node degree
    float* Bd = Dd + (size_t)Nn;                 // NHE : hyperedge size

    // degrees (D and B are contiguous -> one memset)
    hipMemsetAsync(Dd, 0, (size_t)(Nn + NHE) * sizeof(float), stream);
    count_deg<<<(Ee + 255) / 256, 256, 0, stream>>>(hn, he, Dd, Bd);

    // ---- hyperconv layer 1 (128 -> 64) ----
    gemm_x_w1<<<(Nn + 7) / 8, 512, 0, stream>>>(x, Wh1, P0);
    hipMemsetAsync(P2, 0, (size_t)NHE * DIM * sizeof(float), stream);
    scat_fwd<DIM><<<(Ee + 3) / 4, 256, 0, stream>>>(P0, hn, he, P2);
    hipMemsetAsync(P1, 0, (size_t)Nn * DIM * sizeof(float), stream);
    scat_bwd<DIM><<<(Ee + 3) / 4, 256, 0, stream>>>(P2, he, hn, Bd, P1);
    finish_k<DIM, true><<<((size_t)Nn * DIM + 255) / 256, 256, 0, stream>>>(P1, Dd, bh1, P0);

    // ---- hyperconv layer 2 (64 -> 40) ----
    gemm_h_w2<<<(Nn + 7) / 8, 320, 0, stream>>>(P0, Wh2, P3);
    hipMemsetAsync(P2, 0, (size_t)NHE * NCL * sizeof(float), stream);
    scat_fwd<NCL><<<(Ee + 3) / 4, 256, 0, stream>>>(P3, hn, he, P2);
    hipMemsetAsync(P1, 0, (size_t)Nn * NCL * sizeof(float), stream);
    scat_bwd<NCL><<<(Ee + 3) / 4, 256, 0, stream>>>(P2, he, hn, Bd, P1);
    finish_k<NCL, false><<<((size_t)Nn * NCL + 255) / 256, 256, 0, stream>>>(P1, Dd, bh2, P0);

    // ---- head: v = xh2@Wv2+bv2 ; o = v@Wo2+bo2 ; log_softmax ----
    head_k<<<Nn, 64, 0, stream>>>(P0, Wv2, bv2, Wo2, bo2, out);
}

// Round 2
// 1083.777 us; speedup vs baseline: 1.5141x; 1.5141x over previous
//
#include <hip/hip_runtime.h>
#include <math.h>

#define Nn   100000
#define Ee   1600000
#define FIN  128
#define DIM  64
#define NCL  40
#define NHE  50000

// ---------------- GEMM: x[N][128] @ W[128][64] -> out[N][64] ----------------
__global__ __launch_bounds__(512) void gemm_x_w1(const float* __restrict__ x,
                                                 const float* __restrict__ W,
                                                 float* __restrict__ out) {
    __shared__ float Ws[FIN * DIM];   // 32 KB
    __shared__ float xs[8][FIN];      // 4 KB
    int tid = threadIdx.x;
    for (int i = tid; i < FIN * DIM; i += 512) Ws[i] = W[i];
    int row0 = blockIdx.x * 8;
    for (int i = tid; i < 8 * FIN; i += 512) {
        int r = i >> 7, k = i & (FIN - 1);
        int row = row0 + r;
        xs[r][k] = (row < Nn) ? x[(size_t)row * FIN + k] : 0.f;
    }
    __syncthreads();
    int f = tid & 63, r = tid >> 6;
    int row = row0 + r;
    if (row < Nn) {
        float acc = 0.f;
#pragma unroll
        for (int k = 0; k < FIN; ++k) acc = fmaf(xs[r][k], Ws[k * DIM + f], acc);
        out[(size_t)row * DIM + f] = acc;
    }
}

// ---------------- GEMM: xh[N][64] @ W[64][40] -> out[N][40] ----------------
__global__ __launch_bounds__(320) void gemm_h_w2(const float* __restrict__ xh,
                                                 const float* __restrict__ W,
                                                 float* __restrict__ out) {
    __shared__ float Ws[DIM * NCL];   // 10 KB
    __shared__ float xs[8][DIM];      // 2 KB
    int tid = threadIdx.x;  // 0..319
    for (int i = tid; i < DIM * NCL; i += 320) Ws[i] = W[i];
    int row0 = blockIdx.x * 8;
    for (int i = tid; i < 8 * DIM; i += 320) {
        int r = i >> 6, k = i & 63;
        int row = row0 + r;
        xs[r][k] = (row < Nn) ? xh[(size_t)row * DIM + k] : 0.f;
    }
    __syncthreads();
    int f = tid % NCL, r = tid / NCL;
    int row = row0 + r;
    if (row < Nn) {
        float acc = 0.f;
#pragma unroll
        for (int k = 0; k < DIM; ++k) acc = fmaf(xs[r][k], Ws[k * NCL + f], acc);
        out[(size_t)row * NCL + f] = acc;
    }
}

// ---------------- CSR build: count ----------------
__global__ void count_int(const int* __restrict__ hn, const int* __restrict__ he,
                          int* __restrict__ cntN, int* __restrict__ cntH) {
    int i = blockIdx.x * blockDim.x + threadIdx.x;
    if (i < Ee) {
        atomicAdd(&cntN[hn[i]], 1);
        atomicAdd(&cntH[he[i]], 1);
    }
}

// ---------------- CSR build: one-block exclusive scan (grid=2: N and NHE) --
// On exit: cc[i] = exclusive prefix (serves as fill cursor), rp[0..n] = rowptr.
__global__ __launch_bounds__(1024) void scan_two(int* __restrict__ ccN, int* __restrict__ rpN,
                                                 int* __restrict__ ccH, int* __restrict__ rpH) {
    __shared__ int part[1024];
    int* cc; int* rp; int n;
    if (blockIdx.x == 0) { cc = ccN; rp = rpN; n = Nn; }
    else                 { cc = ccH; rp = rpH; n = NHE; }
    int t = threadIdx.x;
    int C = (n + 1023) / 1024;
    int lo = t * C, hi = min(lo + C, n);
    int s = 0;
    for (int i = lo; i < hi; ++i) s += cc[i];
    part[t] = s;
    __syncthreads();
    for (int off = 1; off < 1024; off <<= 1) {
        int v = (t >= off) ? part[t - off] : 0;
        __syncthreads();
        part[t] += v;
        __syncthreads();
    }
    int run = (t == 0) ? 0 : part[t - 1];
    for (int i = lo; i < hi; ++i) {
        int c = cc[i];
        cc[i] = run;
        rp[i] = run;
        run += c;
    }
    if (t == 1023) rp[n] = part[1023];
}

// ---------------- CSR build: fill adjacency ----------------
__global__ void fill_adj(const int* __restrict__ hn, const int* __restrict__ he,
                         int* __restrict__ curN, int* __restrict__ curH,
                         int* __restrict__ adjN, int* __restrict__ adjH) {
    int e = blockIdx.x * blockDim.x + threadIdx.x;
    if (e >= Ee) return;
    int n = hn[e], h = he[e];
    int pn = atomicAdd(&curN[n], 1);
    adjN[pn] = h;
    int ph = atomicAdd(&curH[h], 1);
    adjH[ph] = n;
}

// ---------------- gather: hyperedge side  m_e[h] = Binv * sum xw[members] --
template <int F>
__global__ __launch_bounds__(256) void gather_he(const float* __restrict__ xw,
                                                 const int* __restrict__ rp,
                                                 const int* __restrict__ adj,
                                                 float* __restrict__ me) {
    int h = blockIdx.x * 4 + (threadIdx.x >> 6);
    int f = threadIdx.x & 63;
    if (h >= NHE || f >= F) return;
    int lo = rp[h], hi = rp[h + 1];
    float a0 = 0.f, a1 = 0.f, a2 = 0.f, a3 = 0.f;
    int j = lo;
    for (; j + 3 < hi; j += 4) {
        int n0 = adj[j], n1 = adj[j + 1], n2 = adj[j + 2], n3 = adj[j + 3];
        a0 += xw[(size_t)n0 * F + f];
        a1 += xw[(size_t)n1 * F + f];
        a2 += xw[(size_t)n2 * F + f];
        a3 += xw[(size_t)n3 * F + f];
    }
    for (; j < hi; ++j) a0 += xw[(size_t)adj[j] * F + f];
    float binv = (hi > lo) ? 1.0f / (float)(hi - lo) : 0.f;
    me[(size_t)h * F + f] = ((a0 + a1) + (a2 + a3)) * binv;
}

// ------- gather: node side  out[n] = relu?(Dinv * sum m_e[incident] + b) ---
template <int F, bool RELU>
__global__ __launch_bounds__(256) void gather_n(const float* __restrict__ me,
                                                const int* __restrict__ rp,
                                                const int* __restrict__ adj,
                                                const float* __restrict__ bias,
                                                float* __restrict__ out) {
    int n = blockIdx.x * 4 + (threadIdx.x >> 6);
    int f = threadIdx.x & 63;
    if (n >= Nn || f >= F) return;
    int lo = rp[n], hi = rp[n + 1];
    float a0 = 0.f, a1 = 0.f, a2 = 0.f, a3 = 0.f;
    int j = lo;
    for (; j + 3 < hi; j += 4) {
        int h0 = adj[j], h1 = adj[j + 1], h2 = adj[j + 2], h3 = adj[j + 3];
        a0 += me[(size_t)h0 * F + f];
        a1 += me[(size_t)h1 * F + f];
        a2 += me[(size_t)h2 * F + f];
        a3 += me[(size_t)h3 * F + f];
    }
    for (; j < hi; ++j) a0 += me[(size_t)adj[j] * F + f];
    float dinv = (hi > lo) ? 1.0f / (float)(hi - lo) : 0.f;
    float v = ((a0 + a1) + (a2 + a3)) * dinv + bias[f];
    if (RELU) v = fmaxf(v, 0.f);
    out[(size_t)n * F + f] = v;
}

// ---------------- head: ((xh2 @ Wv + bv) @ Wo + bo) -> log_softmax ----------
__global__ __launch_bounds__(64) void head_k(const float* __restrict__ xh2,
                                             const float* __restrict__ Wv, const float* __restrict__ bv,
                                             const float* __restrict__ Wo, const float* __restrict__ bo,
                                             float* __restrict__ out) {
    __shared__ float row[NCL];
    __shared__ float vbuf[NCL];
    int n = blockIdx.x;
    int t = threadIdx.x;
    if (t < NCL) row[t] = xh2[(size_t)n * NCL + t];
    __syncthreads();
    if (t < NCL) {
        float vv = bv[t];
#pragma unroll
        for (int k = 0; k < NCL; ++k) vv = fmaf(row[k], Wv[k * NCL + t], vv);
        vbuf[t] = vv;
    }
    __syncthreads();
    float o = -INFINITY;
    if (t < NCL) {
        o = bo[t];
#pragma unroll
        for (int k = 0; k < NCL; ++k) o = fmaf(vbuf[k], Wo[k * NCL + t], o);
    }
    float m = o;
#pragma unroll
    for (int off = 32; off >= 1; off >>= 1) m = fmaxf(m, __shfl_xor(m, off));
    float ex = (t < NCL) ? expf(o - m) : 0.f;
    float s = ex;
#pragma unroll
    for (int off = 32; off >= 1; off >>= 1) s += __shfl_xor(s, off);
    if (t < NCL) out[(size_t)n * NCL + t] = o - m - logf(s);
}

extern "C" void kernel_launch(void* const* d_in, const int* in_sizes, int n_in,
                              void* d_out, int out_size, void* d_ws, size_t ws_size,
                              hipStream_t stream) {
    (void)in_sizes; (void)n_in; (void)out_size; (void)ws_size;

    const float* x   = (const float*)d_in[0];
    const int*   hn  = (const int*)d_in[2];
    const int*   he  = (const int*)d_in[3];
    const float* Wh1 = (const float*)d_in[6];
    const float* bh1 = (const float*)d_in[7];
    const float* Wh2 = (const float*)d_in[18];
    const float* bh2 = (const float*)d_in[19];
    const float* Wv2 = (const float*)d_in[24];
    const float* bv2 = (const float*)d_in[25];
    const float* Wo2 = (const float*)d_in[26];
    const float* bo2 = (const float*)d_in[27];
    float* out = (float*)d_out;

    // ---- workspace layout ----
    // A: N*64 floats (25.6MB) : xw1 -> xh -> xh2
    // B: N*40 floats (16MB)   : m_e1 (NHE*64 = 12.8MB) -> xw2 (16MB)
    // C: NHE*40 floats (8MB)  : m_e2
    // ints: curN(N), curH(NHE), rpN(N+1), rpH(NHE+1), adjN(E), adjH(E)
    float* A = (float*)d_ws;
    float* B = A + (size_t)Nn * DIM;
    float* C = B + (size_t)Nn * NCL;
    int*   curN = (int*)(C + (size_t)NHE * NCL);
    int*   curH = curN + Nn;
    int*   rpN  = curH + NHE;
    int*   rpH  = rpN + (Nn + 1);
    int*   adjN = rpH + (NHE + 1);
    int*   adjH = adjN + Ee;

    // ---- CSR build ----
    hipMemsetAsync(curN, 0, (size_t)(Nn + NHE) * sizeof(int), stream);
    count_int<<<(Ee + 255) / 256, 256, 0, stream>>>(hn, he, curN, curH);
    scan_two<<<2, 1024, 0, stream>>>(curN, rpN, curH, rpH);
    fill_adj<<<(Ee + 255) / 256, 256, 0, stream>>>(hn, he, curN, curH, adjN, adjH);

    // ---- hyperconv layer 1 (128 -> 64) ----
    gemm_x_w1<<<(Nn + 7) / 8, 512, 0, stream>>>(x, Wh1, A);
    gather_he<DIM><<<(NHE + 3) / 4, 256, 0, stream>>>(A, rpH, adjH, B);
    gather_n<DIM, true><<<(Nn + 3) / 4, 256, 0, stream>>>(B, rpN, adjN, bh1, A);

    // ---- hyperconv layer 2 (64 -> 40) ----
    gemm_h_w2<<<(Nn + 7) / 8, 320, 0, stream>>>(A, Wh2, B);
    gather_he<NCL><<<(NHE + 3) / 4, 256, 0, stream>>>(B, rpH, adjH, C);
    gather_n<NCL, false><<<(Nn + 3) / 4, 256, 0, stream>>>(C, rpN, adjN, bh2, A);

    // ---- head ----
    head_k<<<Nn, 64, 0, stream>>>(A, Wv2, bv2, Wo2, bo2, out);
}

// Round 3
// 940.117 us; speedup vs baseline: 1.7455x; 1.1528x over previous
//
#include <hip/hip_runtime.h>
#include <math.h>

#define Nn   100000
#define Ee   1600000
#define FIN  128
#define DIM  64
#define NCL  40
#define NHE  50000

// ---------------- GEMM: x[N][128] @ W[128][64] -> out[N][64] ----------------
__global__ __launch_bounds__(512) void gemm_x_w1(const float* __restrict__ x,
                                                 const float* __restrict__ W,
                                                 float* __restrict__ out) {
    __shared__ float Ws[FIN * DIM];   // 32 KB
    __shared__ float xs[8][FIN];      // 4 KB
    int tid = threadIdx.x;
    for (int i = tid; i < FIN * DIM; i += 512) Ws[i] = W[i];
    int row0 = blockIdx.x * 8;
    for (int i = tid; i < 8 * FIN; i += 512) {
        int r = i >> 7, k = i & (FIN - 1);
        int row = row0 + r;
        xs[r][k] = (row < Nn) ? x[(size_t)row * FIN + k] : 0.f;
    }
    __syncthreads();
    int f = tid & 63, r = tid >> 6;
    int row = row0 + r;
    if (row < Nn) {
        float acc = 0.f;
#pragma unroll
        for (int k = 0; k < FIN; ++k) acc = fmaf(xs[r][k], Ws[k * DIM + f], acc);
        out[(size_t)row * DIM + f] = acc;
    }
}

// ---------------- GEMM: xh[N][64] @ W[64][40] -> out[N][40] ----------------
__global__ __launch_bounds__(320) void gemm_h_w2(const float* __restrict__ xh,
                                                 const float* __restrict__ W,
                                                 float* __restrict__ out) {
    __shared__ float Ws[DIM * NCL];   // 10 KB
    __shared__ float xs[8][DIM];      // 2 KB
    int tid = threadIdx.x;  // 0..319
    for (int i = tid; i < DIM * NCL; i += 320) Ws[i] = W[i];
    int row0 = blockIdx.x * 8;
    for (int i = tid; i < 8 * DIM; i += 320) {
        int r = i >> 6, k = i & 63;
        int row = row0 + r;
        xs[r][k] = (row < Nn) ? xh[(size_t)row * DIM + k] : 0.f;
    }
    __syncthreads();
    int f = tid % NCL, r = tid / NCL;
    int row = row0 + r;
    if (row < Nn) {
        float acc = 0.f;
#pragma unroll
        for (int k = 0; k < DIM; ++k) acc = fmaf(xs[r][k], Ws[k * NCL + f], acc);
        out[(size_t)row * NCL + f] = acc;
    }
}

// ---------------- CSR build: count ----------------
__global__ void count_int(const int* __restrict__ hn, const int* __restrict__ he,
                          int* __restrict__ cntN, int* __restrict__ cntH) {
    int i = blockIdx.x * blockDim.x + threadIdx.x;
    if (i < Ee) {
        atomicAdd(&cntN[hn[i]], 1);
        atomicAdd(&cntH[he[i]], 1);
    }
}

// ---------------- CSR build: one-block exclusive scan (grid=2: N and NHE) --
__global__ __launch_bounds__(1024) void scan_two(int* __restrict__ ccN, int* __restrict__ rpN,
                                                 int* __restrict__ ccH, int* __restrict__ rpH) {
    __shared__ int part[1024];
    int* cc; int* rp; int n;
    if (blockIdx.x == 0) { cc = ccN; rp = rpN; n = Nn; }
    else                 { cc = ccH; rp = rpH; n = NHE; }
    int t = threadIdx.x;
    int C = (n + 1023) / 1024;
    int lo = t * C, hi = min(lo + C, n);
    int s = 0;
    for (int i = lo; i < hi; ++i) s += cc[i];
    part[t] = s;
    __syncthreads();
    for (int off = 1; off < 1024; off <<= 1) {
        int v = (t >= off) ? part[t - off] : 0;
        __syncthreads();
        part[t] += v;
        __syncthreads();
    }
    int run = (t == 0) ? 0 : part[t - 1];
    for (int i = lo; i < hi; ++i) {
        int c = cc[i];
        cc[i] = run;
        rp[i] = run;
        run += c;
    }
    if (t == 1023) rp[n] = part[1023];
}

// -------- CSR fill, destination-partitioned by (intended) XCD -------------
// blockIdx%8 == x handles destination node range   [x*12500, (x+1)*12500)
//                       and destination hyperedge  [x*6250,  (x+1)*6250).
// Under round-robin block->XCD mapping, only XCD x ever writes those adj
// regions -> each L2 line is written back once instead of ~8-15x.
// Correct for ANY block->XCD mapping (only locality depends on it).
__global__ __launch_bounds__(256) void fill_adj_part(const int* __restrict__ hn,
                                                     const int* __restrict__ he,
                                                     int* __restrict__ curN, int* __restrict__ curH,
                                                     int* __restrict__ adjN, int* __restrict__ adjH) {
    const int x = blockIdx.x & 7;
    const int nlo = x * (Nn / 8), nhi = nlo + (Nn / 8);
    const int hlo = x * (NHE / 8), hhi = hlo + (NHE / 8);
    const int cls_threads = (gridDim.x >> 3) * blockDim.x;           // threads in my class
    const int t = (blockIdx.x >> 3) * blockDim.x + threadIdx.x;      // my rank in class

    for (int i0 = t * 4; i0 < Ee; i0 += cls_threads * 4) {
        int n0, n1, n2, n3, h0, h1, h2, h3;
        if (i0 + 3 < Ee) {
            int4 nn = *(const int4*)(hn + i0);
            int4 hh = *(const int4*)(he + i0);
            n0 = nn.x; n1 = nn.y; n2 = nn.z; n3 = nn.w;
            h0 = hh.x; h1 = hh.y; h2 = hh.z; h3 = hh.w;
        } else {
            n0 = hn[i0]; h0 = he[i0];
            n1 = (i0 + 1 < Ee) ? hn[i0 + 1] : -1; h1 = (i0 + 1 < Ee) ? he[i0 + 1] : -1;
            n2 = (i0 + 2 < Ee) ? hn[i0 + 2] : -1; h2 = (i0 + 2 < Ee) ? he[i0 + 2] : -1;
            n3 = (i0 + 3 < Ee) ? hn[i0 + 3] : -1; h3 = (i0 + 3 < Ee) ? he[i0 + 3] : -1;
        }
        if (n0 >= nlo && n0 < nhi) adjN[atomicAdd(&curN[n0], 1)] = h0;
        if (n1 >= nlo && n1 < nhi) adjN[atomicAdd(&curN[n1], 1)] = h1;
        if (n2 >= nlo && n2 < nhi) adjN[atomicAdd(&curN[n2], 1)] = h2;
        if (n3 >= nlo && n3 < nhi) adjN[atomicAdd(&curN[n3], 1)] = h3;
        if (h0 >= hlo && h0 < hhi) adjH[atomicAdd(&curH[h0], 1)] = n0;
        if (h1 >= hlo && h1 < hhi) adjH[atomicAdd(&curH[h1], 1)] = n1;
        if (h2 >= hlo && h2 < hhi) adjH[atomicAdd(&curH[h2], 1)] = n2;
        if (h3 >= hlo && h3 < hhi) adjH[atomicAdd(&curH[h3], 1)] = n3;
    }
}

// ---------------- gather: hyperedge side  m_e[h] = Binv * sum xw[members] --
template <int F>
__global__ __launch_bounds__(256) void gather_he(const float* __restrict__ xw,
                                                 const int* __restrict__ rp,
                                                 const int* __restrict__ adj,
                                                 float* __restrict__ me) {
    int h = blockIdx.x * 4 + (threadIdx.x >> 6);
    int f = threadIdx.x & 63;
    if (h >= NHE || f >= F) return;
    int lo = rp[h], hi = rp[h + 1];
    float a0 = 0.f, a1 = 0.f, a2 = 0.f, a3 = 0.f;
    int j = lo;
    for (; j + 3 < hi; j += 4) {
        int n0 = adj[j], n1 = adj[j + 1], n2 = adj[j + 2], n3 = adj[j + 3];
        a0 += xw[(size_t)n0 * F + f];
        a1 += xw[(size_t)n1 * F + f];
        a2 += xw[(size_t)n2 * F + f];
        a3 += xw[(size_t)n3 * F + f];
    }
    for (; j < hi; ++j) a0 += xw[(size_t)adj[j] * F + f];
    float binv = (hi > lo) ? 1.0f / (float)(hi - lo) : 0.f;
    me[(size_t)h * F + f] = ((a0 + a1) + (a2 + a3)) * binv;
}

// ------- gather: node side  out[n] = relu?(Dinv * sum m_e[incident] + b) ---
template <int F, bool RELU>
__global__ __launch_bounds__(256) void gather_n(const float* __restrict__ me,
                                                const int* __restrict__ rp,
                                                const int* __restrict__ adj,
                                                const float* __restrict__ bias,
                                                float* __restrict__ out) {
    int n = blockIdx.x * 4 + (threadIdx.x >> 6);
    int f = threadIdx.x & 63;
    if (n >= Nn || f >= F) return;
    int lo = rp[n], hi = rp[n + 1];
    float a0 = 0.f, a1 = 0.f, a2 = 0.f, a3 = 0.f;
    int j = lo;
    for (; j + 3 < hi; j += 4) {
        int h0 = adj[j], h1 = adj[j + 1], h2 = adj[j + 2], h3 = adj[j + 3];
        a0 += me[(size_t)h0 * F + f];
        a1 += me[(size_t)h1 * F + f];
        a2 += me[(size_t)h2 * F + f];
        a3 += me[(size_t)h3 * F + f];
    }
    for (; j < hi; ++j) a0 += me[(size_t)adj[j] * F + f];
    float dinv = (hi > lo) ? 1.0f / (float)(hi - lo) : 0.f;
    float v = ((a0 + a1) + (a2 + a3)) * dinv + bias[f];
    if (RELU) v = fmaxf(v, 0.f);
    out[(size_t)n * F + f] = v;
}

// ---------------- head: ((xh2 @ Wv + bv) @ Wo + bo) -> log_softmax ----------
__global__ __launch_bounds__(64) void head_k(const float* __restrict__ xh2,
                                             const float* __restrict__ Wv, const float* __restrict__ bv,
                                             const float* __restrict__ Wo, const float* __restrict__ bo,
                                             float* __restrict__ out) {
    __shared__ float row[NCL];
    __shared__ float vbuf[NCL];
    int n = blockIdx.x;
    int t = threadIdx.x;
    if (t < NCL) row[t] = xh2[(size_t)n * NCL + t];
    __syncthreads();
    if (t < NCL) {
        float vv = bv[t];
#pragma unroll
        for (int k = 0; k < NCL; ++k) vv = fmaf(row[k], Wv[k * NCL + t], vv);
        vbuf[t] = vv;
    }
    __syncthreads();
    float o = -INFINITY;
    if (t < NCL) {
        o = bo[t];
#pragma unroll
        for (int k = 0; k < NCL; ++k) o = fmaf(vbuf[k], Wo[k * NCL + t], o);
    }
    float m = o;
#pragma unroll
    for (int off = 32; off >= 1; off >>= 1) m = fmaxf(m, __shfl_xor(m, off));
    float ex = (t < NCL) ? expf(o - m) : 0.f;
    float s = ex;
#pragma unroll
    for (int off = 32; off >= 1; off >>= 1) s += __shfl_xor(s, off);
    if (t < NCL) out[(size_t)n * NCL + t] = o - m - logf(s);
}

extern "C" void kernel_launch(void* const* d_in, const int* in_sizes, int n_in,
                              void* d_out, int out_size, void* d_ws, size_t ws_size,
                              hipStream_t stream) {
    (void)in_sizes; (void)n_in; (void)out_size; (void)ws_size;

    const float* x   = (const float*)d_in[0];
    const int*   hn  = (const int*)d_in[2];
    const int*   he  = (const int*)d_in[3];
    const float* Wh1 = (const float*)d_in[6];
    const float* bh1 = (const float*)d_in[7];
    const float* Wh2 = (const float*)d_in[18];
    const float* bh2 = (const float*)d_in[19];
    const float* Wv2 = (const float*)d_in[24];
    const float* bv2 = (const float*)d_in[25];
    const float* Wo2 = (const float*)d_in[26];
    const float* bo2 = (const float*)d_in[27];
    float* out = (float*)d_out;

    // ---- workspace layout ----
    float* A = (float*)d_ws;                       // N*64  : xw1 -> xh -> xh2
    float* B = A + (size_t)Nn * DIM;               // max(NHE*64, N*40)
    float* C = B + (size_t)Nn * NCL;               // NHE*40
    int*   curN = (int*)(C + (size_t)NHE * NCL);
    int*   curH = curN + Nn;
    int*   rpN  = curH + NHE;
    int*   rpH  = rpN + (Nn + 1);
    int*   adjN = rpH + (NHE + 1);
    int*   adjH = adjN + Ee;

    // ---- CSR build ----
    hipMemsetAsync(curN, 0, (size_t)(Nn + NHE) * sizeof(int), stream);
    count_int<<<(Ee + 255) / 256, 256, 0, stream>>>(hn, he, curN, curH);
    scan_two<<<2, 1024, 0, stream>>>(curN, rpN, curH, rpH);
    fill_adj_part<<<2048, 256, 0, stream>>>(hn, he, curN, curH, adjN, adjH);

    // ---- hyperconv layer 1 (128 -> 64) ----
    gemm_x_w1<<<(Nn + 7) / 8, 512, 0, stream>>>(x, Wh1, A);
    gather_he<DIM><<<(NHE + 3) / 4, 256, 0, stream>>>(A, rpH, adjH, B);
    gather_n<DIM, true><<<(Nn + 3) / 4, 256, 0, stream>>>(B, rpN, adjN, bh1, A);

    // ---- hyperconv layer 2 (64 -> 40) ----
    gemm_h_w2<<<(Nn + 7) / 8, 320, 0, stream>>>(A, Wh2, B);
    gather_he<NCL><<<(NHE + 3) / 4, 256, 0, stream>>>(B, rpH, adjH, C);
    gather_n<NCL, false><<<(Nn + 3) / 4, 256, 0, stream>>>(C, rpN, adjN, bh2, A);

    // ---- head ----
    head_k<<<Nn, 64, 0, stream>>>(A, Wv2, bv2, Wo2, bo2, out);
}

// Round 4
// 730.561 us; speedup vs baseline: 2.2461x; 1.2868x over previous
//
#include <hip/hip_runtime.h>
#include <math.h>

#define Nn   100000
#define Ee   1600000
#define FIN  128
#define DIM  64
#define NCL  40
#define NHE  50000

#define NBN  ((Nn  + 1023) >> 10)   // 98 scan blocks for node counts
#define NBH  ((NHE + 1023) >> 10)   // 49 scan blocks for hyperedge counts

// ---------------- GEMM: x[N][128] @ W[128][64] -> out[N][64] ----------------
__global__ __launch_bounds__(512) void gemm_x_w1(const float* __restrict__ x,
                                                 const float* __restrict__ W,
                                                 float* __restrict__ out) {
    __shared__ float Ws[FIN * DIM];   // 32 KB
    __shared__ float xs[8][FIN];      // 4 KB
    int tid = threadIdx.x;
    for (int i = tid; i < FIN * DIM; i += 512) Ws[i] = W[i];
    int row0 = blockIdx.x * 8;
    for (int i = tid; i < 8 * FIN; i += 512) {
        int r = i >> 7, k = i & (FIN - 1);
        int row = row0 + r;
        xs[r][k] = (row < Nn) ? x[(size_t)row * FIN + k] : 0.f;
    }
    __syncthreads();
    int f = tid & 63, r = tid >> 6;
    int row = row0 + r;
    if (row < Nn) {
        float acc = 0.f;
#pragma unroll
        for (int k = 0; k < FIN; ++k) acc = fmaf(xs[r][k], Ws[k * DIM + f], acc);
        out[(size_t)row * DIM + f] = acc;
    }
}

// ---------------- GEMM: xh[N][64] @ W[64][40] -> out[N][40] ----------------
__global__ __launch_bounds__(320) void gemm_h_w2(const float* __restrict__ xh,
                                                 const float* __restrict__ W,
                                                 float* __restrict__ out) {
    __shared__ float Ws[DIM * NCL];   // 10 KB
    __shared__ float xs[8][DIM];      // 2 KB
    int tid = threadIdx.x;  // 0..319
    for (int i = tid; i < DIM * NCL; i += 320) Ws[i] = W[i];
    int row0 = blockIdx.x * 8;
    for (int i = tid; i < 8 * DIM; i += 320) {
        int r = i >> 6, k = i & 63;
        int row = row0 + r;
        xs[r][k] = (row < Nn) ? xh[(size_t)row * DIM + k] : 0.f;
    }
    __syncthreads();
    int f = tid % NCL, r = tid / NCL;
    int row = row0 + r;
    if (row < Nn) {
        float acc = 0.f;
#pragma unroll
        for (int k = 0; k < DIM; ++k) acc = fmaf(xs[r][k], Ws[k * NCL + f], acc);
        out[(size_t)row * NCL + f] = acc;
    }
}

// -------- count, destination-partitioned (same trick as fill) --------------
__global__ __launch_bounds__(256) void count_int_part(const int* __restrict__ hn,
                                                      const int* __restrict__ he,
                                                      int* __restrict__ cntN, int* __restrict__ cntH) {
    const int x = blockIdx.x & 7;
    const int nlo = x * (Nn / 8), nhi = nlo + (Nn / 8);
    const int hlo = x * (NHE / 8), hhi = hlo + (NHE / 8);
    const int cls_threads = (gridDim.x >> 3) * blockDim.x;
    const int t = (blockIdx.x >> 3) * blockDim.x + threadIdx.x;
    for (int i0 = t * 4; i0 < Ee; i0 += cls_threads * 4) {
        int n0, n1, n2, n3, h0, h1, h2, h3;
        if (i0 + 3 < Ee) {
            int4 nn = *(const int4*)(hn + i0);
            int4 hh = *(const int4*)(he + i0);
            n0 = nn.x; n1 = nn.y; n2 = nn.z; n3 = nn.w;
            h0 = hh.x; h1 = hh.y; h2 = hh.z; h3 = hh.w;
        } else {
            n0 = hn[i0]; h0 = he[i0];
            n1 = (i0 + 1 < Ee) ? hn[i0 + 1] : -1; h1 = (i0 + 1 < Ee) ? he[i0 + 1] : -1;
            n2 = (i0 + 2 < Ee) ? hn[i0 + 2] : -1; h2 = (i0 + 2 < Ee) ? he[i0 + 2] : -1;
            n3 = (i0 + 3 < Ee) ? hn[i0 + 3] : -1; h3 = (i0 + 3 < Ee) ? he[i0 + 3] : -1;
        }
        if (n0 >= nlo && n0 < nhi) atomicAdd(&cntN[n0], 1);
        if (n1 >= nlo && n1 < nhi) atomicAdd(&cntN[n1], 1);
        if (n2 >= nlo && n2 < nhi) atomicAdd(&cntN[n2], 1);
        if (n3 >= nlo && n3 < nhi) atomicAdd(&cntN[n3], 1);
        if (h0 >= hlo && h0 < hhi) atomicAdd(&cntH[h0], 1);
        if (h1 >= hlo && h1 < hhi) atomicAdd(&cntH[h1], 1);
        if (h2 >= hlo && h2 < hhi) atomicAdd(&cntH[h2], 1);
        if (h3 >= hlo && h3 < hhi) atomicAdd(&cntH[h3], 1);
    }
}

// ---------------- scan phase 1: block-local scan (1024 elems/block) --------
// Writes block-local EXCLUSIVE prefix into rp[], block total into bsum[].
__global__ __launch_bounds__(256) void scan_p1(const int* __restrict__ ccN, int* __restrict__ rpN,
                                               const int* __restrict__ ccH, int* __restrict__ rpH,
                                               int* __restrict__ bsum) {
    int b = blockIdx.x;
    const int* cc; int* rp; int n; int blk;
    if (b < NBN) { cc = ccN; rp = rpN; n = Nn;  blk = b; }
    else         { cc = ccH; rp = rpH; n = NHE; blk = b - NBN; }
    int t = threadIdx.x;
    int i0 = (blk << 10) + t * 4;
    int4 v = make_int4(0, 0, 0, 0);
    if (i0 + 3 < n) v = *(const int4*)(cc + i0);
    else {
        if (i0     < n) v.x = cc[i0];
        if (i0 + 1 < n) v.y = cc[i0 + 1];
        if (i0 + 2 < n) v.z = cc[i0 + 2];
        if (i0 + 3 < n) v.w = cc[i0 + 3];
    }
    int s = v.x + v.y + v.z + v.w;
    int lane = t & 63, w = t >> 6;
    int sc = s;
#pragma unroll
    for (int off = 1; off < 64; off <<= 1) {
        int u = __shfl_up(sc, off);
        if (lane >= off) sc += u;
    }
    __shared__ int wsum[4];
    if (lane == 63) wsum[w] = sc;
    __syncthreads();
    int woff = 0;
    for (int k = 0; k < w; ++k) woff += wsum[k];
    int excl = woff + sc - s;
    int4 o;
    o.x = excl; o.y = o.x + v.x; o.z = o.y + v.y; o.w = o.z + v.z;
    if (i0 + 3 < n) *(int4*)(rp + i0) = o;
    else {
        if (i0     < n) rp[i0]     = o.x;
        if (i0 + 1 < n) rp[i0 + 1] = o.y;
        if (i0 + 2 < n) rp[i0 + 2] = o.z;
        if (i0 + 3 < n) rp[i0 + 3] = o.w;
    }
    if (t == 255) bsum[b] = woff + sc;
}

// ---------------- scan phase 2: scan the 147 block totals (segmented) ------
__global__ __launch_bounds__(256) void scan_p2(int* __restrict__ bsum,
                                               int* __restrict__ rpN, int* __restrict__ rpH) {
    const int TOT = NBN + NBH;
    int t = threadIdx.x;
    __shared__ int sh[256];
    int v = (t < TOT) ? bsum[t] : 0;
    sh[t] = v;
    __syncthreads();
#pragma unroll
    for (int off = 1; off < 256; off <<= 1) {
        int u = 0;
        if (t >= off && ((t - off < NBN) == (t < NBN))) u = sh[t - off];
        __syncthreads();
        sh[t] += u;
        __syncthreads();
    }
    if (t < TOT) bsum[t] = sh[t] - v;          // exclusive block offset
    if (t == NBN - 1) rpN[Nn]  = sh[t];        // segment totals
    if (t == TOT - 1) rpH[NHE] = sh[t];
}

// ---------------- scan phase 3: add block offsets, write rp and cursors ----
__global__ __launch_bounds__(256) void scan_p3(int* __restrict__ ccN, int* __restrict__ rpN,
                                               int* __restrict__ ccH, int* __restrict__ rpH,
                                               const int* __restrict__ bsum) {
    int b = blockIdx.x;
    int* cc; int* rp; int n; int blk;
    if (b < NBN) { cc = ccN; rp = rpN; n = Nn;  blk = b; }
    else         { cc = ccH; rp = rpH; n = NHE; blk = b - NBN; }
    int off = bsum[b];
    int t = threadIdx.x;
    int i0 = (blk << 10) + t * 4;
    if (i0 + 3 < n) {
        int4 v = *(const int4*)(rp + i0);
        v.x += off; v.y += off; v.z += off; v.w += off;
        *(int4*)(rp + i0) = v;
        *(int4*)(cc + i0) = v;
    } else {
        for (int k = 0; k < 4; ++k)
            if (i0 + k < n) { int u = rp[i0 + k] + off; rp[i0 + k] = u; cc[i0 + k] = u; }
    }
}

// -------- CSR fill, destination-partitioned by (intended) XCD -------------
__global__ __launch_bounds__(256) void fill_adj_part(const int* __restrict__ hn,
                                                     const int* __restrict__ he,
                                                     int* __restrict__ curN, int* __restrict__ curH,
                                                     int* __restrict__ adjN, int* __restrict__ adjH) {
    const int x = blockIdx.x & 7;
    const int nlo = x * (Nn / 8), nhi = nlo + (Nn / 8);
    const int hlo = x * (NHE / 8), hhi = hlo + (NHE / 8);
    const int cls_threads = (gridDim.x >> 3) * blockDim.x;
    const int t = (blockIdx.x >> 3) * blockDim.x + threadIdx.x;

    for (int i0 = t * 4; i0 < Ee; i0 += cls_threads * 4) {
        int n0, n1, n2, n3, h0, h1, h2, h3;
        if (i0 + 3 < Ee) {
            int4 nn = *(const int4*)(hn + i0);
            int4 hh = *(const int4*)(he + i0);
            n0 = nn.x; n1 = nn.y; n2 = nn.z; n3 = nn.w;
            h0 = hh.x; h1 = hh.y; h2 = hh.z; h3 = hh.w;
        } else {
            n0 = hn[i0]; h0 = he[i0];
            n1 = (i0 + 1 < Ee) ? hn[i0 + 1] : -1; h1 = (i0 + 1 < Ee) ? he[i0 + 1] : -1;
            n2 = (i0 + 2 < Ee) ? hn[i0 + 2] : -1; h2 = (i0 + 2 < Ee) ? he[i0 + 2] : -1;
            n3 = (i0 + 3 < Ee) ? hn[i0 + 3] : -1; h3 = (i0 + 3 < Ee) ? he[i0 + 3] : -1;
        }
        if (n0 >= nlo && n0 < nhi) adjN[atomicAdd(&curN[n0], 1)] = h0;
        if (n1 >= nlo && n1 < nhi) adjN[atomicAdd(&curN[n1], 1)] = h1;
        if (n2 >= nlo && n2 < nhi) adjN[atomicAdd(&curN[n2], 1)] = h2;
        if (n3 >= nlo && n3 < nhi) adjN[atomicAdd(&curN[n3], 1)] = h3;
        if (h0 >= hlo && h0 < hhi) adjH[atomicAdd(&curH[h0], 1)] = n0;
        if (h1 >= hlo && h1 < hhi) adjH[atomicAdd(&curH[h1], 1)] = n1;
        if (h2 >= hlo && h2 < hhi) adjH[atomicAdd(&curH[h2], 1)] = n2;
        if (h3 >= hlo && h3 < hhi) adjH[atomicAdd(&curH[h3], 1)] = n3;
    }
}

// ---------------- gather: hyperedge side  m_e[h] = Binv * sum xw[members] --
template <int F>
__global__ __launch_bounds__(256) void gather_he(const float* __restrict__ xw,
                                                 const int* __restrict__ rp,
                                                 const int* __restrict__ adj,
                                                 float* __restrict__ me) {
    int h = blockIdx.x * 4 + (threadIdx.x >> 6);
    int f = threadIdx.x & 63;
    if (h >= NHE || f >= F) return;
    int lo = rp[h], hi = rp[h + 1];
    float a0 = 0.f, a1 = 0.f, a2 = 0.f, a3 = 0.f;
    int j = lo;
    for (; j + 3 < hi; j += 4) {
        int n0 = adj[j], n1 = adj[j + 1], n2 = adj[j + 2], n3 = adj[j + 3];
        a0 += xw[(size_t)n0 * F + f];
        a1 += xw[(size_t)n1 * F + f];
        a2 += xw[(size_t)n2 * F + f];
        a3 += xw[(size_t)n3 * F + f];
    }
    for (; j < hi; ++j) a0 += xw[(size_t)adj[j] * F + f];
    float binv = (hi > lo) ? 1.0f / (float)(hi - lo) : 0.f;
    me[(size_t)h * F + f] = ((a0 + a1) + (a2 + a3)) * binv;
}

// ------- gather: node side  out[n] = relu?(Dinv * sum m_e[incident] + b) ---
template <int F, bool RELU>
__global__ __launch_bounds__(256) void gather_n(const float* __restrict__ me,
                                                const int* __restrict__ rp,
                                                const int* __restrict__ adj,
                                                const float* __restrict__ bias,
                                                float* __restrict__ out) {
    int n = blockIdx.x * 4 + (threadIdx.x >> 6);
    int f = threadIdx.x & 63;
    if (n >= Nn || f >= F) return;
    int lo = rp[n], hi = rp[n + 1];
    float a0 = 0.f, a1 = 0.f, a2 = 0.f, a3 = 0.f;
    int j = lo;
    for (; j + 3 < hi; j += 4) {
        int h0 = adj[j], h1 = adj[j + 1], h2 = adj[j + 2], h3 = adj[j + 3];
        a0 += me[(size_t)h0 * F + f];
        a1 += me[(size_t)h1 * F + f];
        a2 += me[(size_t)h2 * F + f];
        a3 += me[(size_t)h3 * F + f];
    }
    for (; j < hi; ++j) a0 += me[(size_t)adj[j] * F + f];
    float dinv = (hi > lo) ? 1.0f / (float)(hi - lo) : 0.f;
    float v = ((a0 + a1) + (a2 + a3)) * dinv + bias[f];
    if (RELU) v = fmaxf(v, 0.f);
    out[(size_t)n * F + f] = v;
}

// ---------------- head: ((xh2 @ Wv + bv) @ Wo + bo) -> log_softmax ----------
__global__ __launch_bounds__(64) void head_k(const float* __restrict__ xh2,
                                             const float* __restrict__ Wv, const float* __restrict__ bv,
                                             const float* __restrict__ Wo, const float* __restrict__ bo,
                                             float* __restrict__ out) {
    __shared__ float row[NCL];
    __shared__ float vbuf[NCL];
    int n = blockIdx.x;
    int t = threadIdx.x;
    if (t < NCL) row[t] = xh2[(size_t)n * NCL + t];
    __syncthreads();
    if (t < NCL) {
        float vv = bv[t];
#pragma unroll
        for (int k = 0; k < NCL; ++k) vv = fmaf(row[k], Wv[k * NCL + t], vv);
        vbuf[t] = vv;
    }
    __syncthreads();
    float o = -INFINITY;
    if (t < NCL) {
        o = bo[t];
#pragma unroll
        for (int k = 0; k < NCL; ++k) o = fmaf(vbuf[k], Wo[k * NCL + t], o);
    }
    float m = o;
#pragma unroll
    for (int off = 32; off >= 1; off >>= 1) m = fmaxf(m, __shfl_xor(m, off));
    float ex = (t < NCL) ? expf(o - m) : 0.f;
    float s = ex;
#pragma unroll
    for (int off = 32; off >= 1; off >>= 1) s += __shfl_xor(s, off);
    if (t < NCL) out[(size_t)n * NCL + t] = o - m - logf(s);
}

extern "C" void kernel_launch(void* const* d_in, const int* in_sizes, int n_in,
                              void* d_out, int out_size, void* d_ws, size_t ws_size,
                              hipStream_t stream) {
    (void)in_sizes; (void)n_in; (void)out_size; (void)ws_size;

    const float* x   = (const float*)d_in[0];
    const int*   hn  = (const int*)d_in[2];
    const int*   he  = (const int*)d_in[3];
    const float* Wh1 = (const float*)d_in[6];
    const float* bh1 = (const float*)d_in[7];
    const float* Wh2 = (const float*)d_in[18];
    const float* bh2 = (const float*)d_in[19];
    const float* Wv2 = (const float*)d_in[24];
    const float* bv2 = (const float*)d_in[25];
    const float* Wo2 = (const float*)d_in[26];
    const float* bo2 = (const float*)d_in[27];
    float* out = (float*)d_out;

    // ---- workspace layout ----
    float* A = (float*)d_ws;                       // N*64  : xw1 -> xh -> xh2
    float* B = A + (size_t)Nn * DIM;               // max(NHE*64, N*40)
    float* C = B + (size_t)Nn * NCL;               // NHE*40
    int*   curN = (int*)(C + (size_t)NHE * NCL);
    int*   curH = curN + Nn;
    int*   rpN  = curH + NHE;
    int*   rpH  = rpN + (Nn + 1);
    int*   adjN = rpH + (NHE + 1);
    int*   adjH = adjN + Ee;
    int*   bsum = adjH + Ee;                       // NBN+NBH block totals

    // ---- CSR build ----
    hipMemsetAsync(curN, 0, (size_t)(Nn + NHE) * sizeof(int), stream);
    count_int_part<<<2048, 256, 0, stream>>>(hn, he, curN, curH);
    scan_p1<<<NBN + NBH, 256, 0, stream>>>(curN, rpN, curH, rpH, bsum);
    scan_p2<<<1, 256, 0, stream>>>(bsum, rpN, rpH);
    scan_p3<<<NBN + NBH, 256, 0, stream>>>(curN, rpN, curH, rpH, bsum);
    fill_adj_part<<<2048, 256, 0, stream>>>(hn, he, curN, curH, adjN, adjH);

    // ---- hyperconv layer 1 (128 -> 64) ----
    gemm_x_w1<<<(Nn + 7) / 8, 512, 0, stream>>>(x, Wh1, A);
    gather_he<DIM><<<(NHE + 3) / 4, 256, 0, stream>>>(A, rpH, adjH, B);
    gather_n<DIM, true><<<(Nn + 3) / 4, 256, 0, stream>>>(B, rpN, adjN, bh1, A);

    // ---- hyperconv layer 2 (64 -> 40) ----
    gemm_h_w2<<<(Nn + 7) / 8, 320, 0, stream>>>(A, Wh2, B);
    gather_he<NCL><<<(NHE + 3) / 4, 256, 0, stream>>>(B, rpH, adjH, C);
    gather_n<NCL, false><<<(Nn + 3) / 4, 256, 0, stream>>>(C, rpN, adjN, bh2, A);

    // ---- head ----
    head_k<<<Nn, 64, 0, stream>>>(A, Wv2, bv2, Wo2, bo2, out);
}